// Round 12
// baseline (311.891 us; speedup 1.0000x reference)
//
#include <hip/hip_runtime.h>
#include <math.h>

#define T_TOK 4096
#define DM 1024
#define HID 4096
#define NEXP 8

typedef unsigned short u16;
typedef __attribute__((ext_vector_type(8))) short short8;
typedef __attribute__((ext_vector_type(4))) float f32x4;

__device__ __forceinline__ u16 f2bf(float f){
  unsigned u = __float_as_uint(f);
  u += 0x7FFF + ((u >> 16) & 1);
  return (u16)(u >> 16);
}

// ---- workspace layout (byte offsets) ----
#define GATE_OFF   0u          // float[4096]
#define CNT_OFF    16384u      // int[8]
#define LIST_OFF   16512u      // int[8][4096]
#define PROBS_OFF  147584u     // float[4096][8]
#define XB_OFF     278656u     // bf16[4096][1024]
#define H_OFF      8667264u    // bf16[4096][4096]
#define PART_OFF   42221696u   // float[4][4096][1024] = 64MB

__device__ __forceinline__ void glds16(const void* g, void* l){
  __builtin_amdgcn_global_load_lds((const __attribute__((address_space(1))) void*)g,
                                   (__attribute__((address_space(3))) void*)l, 16, 0, 0);
}

__global__ void zero_cnt_kernel(int* cnt){
  if (threadIdx.x < NEXP) cnt[threadIdx.x] = 0;
}

// one wave per token: gating + routing + x->bf16 conversion
__global__ __launch_bounds__(256) void gate_kernel(
    const float* __restrict__ x, const float* __restrict__ gw,
    float* __restrict__ gateo, int* __restrict__ cnt, int* __restrict__ list,
    float* __restrict__ probs, u16* __restrict__ xb)
{
  int tid = threadIdx.x;
  int lane = tid & 63;
  int w = tid >> 6;
  int t = blockIdx.x * 4 + w;

  const float4* x4 = (const float4*)(x + (size_t)t * DM);
  const float4* g4 = (const float4*)gw;

  float acc[8] = {0,0,0,0,0,0,0,0};
  #pragma unroll
  for (int i = 0; i < 4; i++){
    int p = i * 64 + lane;
    float4 xv = x4[p];
    ushort4 pk;
    pk.x = f2bf(xv.x); pk.y = f2bf(xv.y); pk.z = f2bf(xv.z); pk.w = f2bf(xv.w);
    *(ushort4*)&xb[(size_t)t * DM + (size_t)p * 4] = pk;
    #pragma unroll
    for (int e = 0; e < NEXP; e++){
      float4 gv = g4[e * 256 + p];
      acc[e] += xv.x * gv.x + xv.y * gv.y + xv.z * gv.z + xv.w * gv.w;
    }
  }
  #pragma unroll
  for (int e = 0; e < NEXP; e++){
    #pragma unroll
    for (int off = 32; off; off >>= 1)
      acc[e] += __shfl_xor(acc[e], off);
  }
  if (lane == 0){
    float mx = acc[0];
    #pragma unroll
    for (int e = 1; e < NEXP; e++) mx = fmaxf(mx, acc[e]);
    float p[8]; float s = 0.f;
    #pragma unroll
    for (int e = 0; e < NEXP; e++){ p[e] = expf(acc[e] - mx); s += p[e]; }
    float inv = 1.f / s;
    int be = 0; float bp = p[0];
    #pragma unroll
    for (int e = 1; e < NEXP; e++){ if (p[e] > bp){ bp = p[e]; be = e; } }
    #pragma unroll
    for (int e = 0; e < NEXP; e++) probs[(size_t)t * 8 + e] = p[e] * inv;
    gateo[t] = bp * inv;
    int pos = atomicAdd(&cnt[be], 1);
    list[be * T_TOK + pos] = t;
  }
}

// deterministic aux-loss reduction, one block
__global__ __launch_bounds__(256) void aux_kernel(
    const float* __restrict__ probs, const int* __restrict__ cnt,
    float* __restrict__ aux_out)
{
  __shared__ float sm[256 * 8];
  int tid = threadIdx.x;
  float s[8] = {0,0,0,0,0,0,0,0};
  for (int i = 0; i < 16; i++){
    int t = i * 256 + tid;
    #pragma unroll
    for (int e = 0; e < 8; e++) s[e] += probs[(size_t)t * 8 + e];
  }
  #pragma unroll
  for (int e = 0; e < 8; e++) sm[tid * 8 + e] = s[e];
  __syncthreads();
  for (int st = 128; st; st >>= 1){
    if (tid < st){
      #pragma unroll
      for (int e = 0; e < 8; e++) sm[tid * 8 + e] += sm[(tid + st) * 8 + e];
    }
    __syncthreads();
  }
  if (tid == 0){
    float a = 0.f;
    #pragma unroll
    for (int e = 0; e < 8; e++){
      float f = (float)cnt[e] / (float)T_TOK;
      float P = sm[e] / (float)T_TOK;
      a += f * P;
    }
    aux_out[0] = 0.01f * (float)NEXP * a;
  }
}

// Grouped GEMM, m97 structure (128x128, BK=64, 4 waves, single 32KB LDS buf,
// 2 barriers/K-step, lb(256,3)) — R11 internals — with XCD-pinned 2D windows:
// window = 32 blocks = (4 mt) x (8 nt) [PHASE2: x fixed sk] sharing ~1MB A rows
// + 4MB B panel; all 32 land on one XCD (bid%8 = W%8) so re-reads hit the 4MB
// per-XCD L2 instead of L3 fabric (T1 mechanism).
//   bid = (W%8) + 8*(W/8*32 + j);  inverse: x=bid&7; r=bid>>3; j=r&31; W=(r>>5)*8+x
//   W -> (e,g,c) by scanning cnt: expert e owns Ge*4 windows (Ge=ceil(Te/4),
//   Te=ceil(ne/128)); g = mt-group, c = ntg (GEMM1) or sk (GEMM2).
//   j -> dm=j>>3 (mt within group), dn=j&7 (nt within group).
// PHASE2=false: A=xb, B=w1 -> h = gelu(acc+b1) bf16
// PHASE2=true : A=h,  B=w2 -> PART[sk][tok][col] = acc (+b2 if sk==0) fp32
template<int ASTR, int BSTR, int NTOT, int KS, bool PHASE2>
__global__ __launch_bounds__(256, 3) void ffn_gemm(
    const u16*  __restrict__ Aall,
    const float* __restrict__ Bf,    // fp32 weights [E][NTOT][BSTR]
    const float* __restrict__ bias,
    const int*  __restrict__ cnt,
    const int*  __restrict__ list,
    u16*  __restrict__ hOut,
    float* __restrict__ pOut)
{
  int bid = blockIdx.x;
  int x  = bid & 7;
  int r  = bid >> 3;
  int j  = r & 31;
  int Wq = r >> 5;
  int W  = Wq * 8 + x;
  int dm = j >> 3, dn = j & 7;

  // scan experts -> (e, g, c)
  int e = -1, g = 0, c = 0, Te = 0, accW = 0;
  #pragma unroll
  for (int i = 0; i < NEXP; i++){
    int ti = (cnt[i] + 127) >> 7;
    int wi = ((ti + 3) >> 2) * 4;
    if (e < 0 && W < accW + wi){
      int Wl = W - accW; e = i; g = Wl >> 2; c = Wl & 3; Te = ti;
    }
    accW += wi;
  }
  if (e < 0) return;
  int mt = g * 4 + dm;
  if (mt >= Te) return;
  int ne = cnt[e];
  int m0 = mt * 128;
  const int* lst = list + e * T_TOK;
  int nt = PHASE2 ? dn : (c * 8 + dn);
  int sk = PHASE2 ? c : 0;
  int n0 = nt * 128;
  int koff = sk * (KS * 64);

  __shared__ u16 As[8192];           // [128][64] swizzled, 16KB
  __shared__ u16 Bs[8192];

  int tid  = threadIdx.x;
  int lane = tid & 63;
  int w    = tid >> 6;               // 4 waves
  int wm = w >> 1, wn = w & 1;       // 2M x 2N; wave out 64x64
  int fr = lane & 15, fq = lane >> 4;

  // A staging via glds: 16 segs of 1KB (8 rows x 64 cols); wave owns 4.
  // lane l -> row seg*8+(l>>3); fetches global chunk g=(l&7)^(row&7) so
  // LDS[row][slot] holds global chunk slot^(row&7) (both-sides swizzle).
  const u16* aS[4]; int aDst[4];
  #pragma unroll
  for (int i = 0; i < 4; i++){
    int seg = w * 4 + i;
    int rr  = seg * 8 + (lane >> 3);
    int gg  = (lane & 7) ^ (rr & 7);
    int mrow = m0 + rr; if (mrow > ne - 1) mrow = ne - 1;
    aS[i] = Aall + (size_t)lst[mrow] * ASTR + koff + gg * 8;
    aDst[i] = seg * 512;
  }

  // B reg-staging: 1024 chunks (128 rows x 8 slots of 8 bf16); thread owns 4.
  const float* bS[4]; int bDst[4];
  #pragma unroll
  for (int i = 0; i < 4; i++){
    int cc = i * 256 + tid;
    int rr = cc >> 3, sl = cc & 7;
    int gg = sl ^ (rr & 7);
    bS[i] = Bf + ((size_t)e * NTOT + n0 + rr) * BSTR + koff + gg * 8;
    bDst[i] = rr * 64 + sl * 8;
  }

  f32x4 acc[4][4];
  #pragma unroll
  for (int m = 0; m < 4; m++)
    #pragma unroll
    for (int n = 0; n < 4; n++)
      acc[m][n] = (f32x4){0.f, 0.f, 0.f, 0.f};

  float4 br0[4], br1[4];
  #pragma unroll
  for (int i = 0; i < 4; i++){
    const float4* s = (const float4*)bS[i];
    br0[i] = s[0]; br1[i] = s[1];
  }

  for (int ks = 0; ks < KS; ++ks){
    if (ks) __syncthreads();         // all waves done reading LDS (lgkm drained)
    size_t ko = (size_t)ks * 64;
    #pragma unroll
    for (int i = 0; i < 4; i++) glds16(aS[i] + ko, &As[aDst[i]]);
    // write B(ks) from regs (cvt fp32->bf16, swizzled chunks)
    #pragma unroll
    for (int i = 0; i < 4; i++){
      uint4 pk;
      pk.x = (unsigned)f2bf(br0[i].x) | ((unsigned)f2bf(br0[i].y) << 16);
      pk.y = (unsigned)f2bf(br0[i].z) | ((unsigned)f2bf(br0[i].w) << 16);
      pk.z = (unsigned)f2bf(br1[i].x) | ((unsigned)f2bf(br1[i].y) << 16);
      pk.w = (unsigned)f2bf(br1[i].z) | ((unsigned)f2bf(br1[i].w) << 16);
      *(uint4*)&Bs[bDst[i]] = pk;
    }
    // issue B(ks+1) reg loads; drain at the barrier with glds-A
    if (ks + 1 < KS){
      #pragma unroll
      for (int i = 0; i < 4; i++){
        const float4* s = (const float4*)(bS[i] + (ks + 1) * 64);
        br0[i] = s[0]; br1[i] = s[1];
      }
    }
    __syncthreads();                 // vmcnt(0)+lgkm drain: tile resident
    #pragma unroll
    for (int kc = 0; kc < 2; kc++){
      short8 afr[4], bfr[4];
      #pragma unroll
      for (int m = 0; m < 4; m++){
        int row  = wm * 64 + m * 16 + fr;
        int slot = (kc * 4 + fq) ^ (row & 7);
        afr[m] = *(const short8*)&As[row * 64 + slot * 8];
      }
      #pragma unroll
      for (int n = 0; n < 4; n++){
        int row  = wn * 64 + n * 16 + fr;
        int slot = (kc * 4 + fq) ^ (row & 7);
        bfr[n] = *(const short8*)&Bs[row * 64 + slot * 8];
      }
      #pragma unroll
      for (int m = 0; m < 4; m++)
        #pragma unroll
        for (int n = 0; n < 4; n++)
          acc[m][n] = __builtin_amdgcn_mfma_f32_16x16x32_bf16(afr[m], bfr[n], acc[m][n], 0, 0, 0);
    }
  }

  // epilogue: C frag layout col = lane&15, row = (lane>>4)*4 + i
  #pragma unroll
  for (int n = 0; n < 4; n++){
    int col = n0 + wn * 64 + n * 16 + fr;
    float bv = bias[(size_t)e * NTOT + col];
    if (PHASE2 && sk != 0) bv = 0.f;
    #pragma unroll
    for (int m = 0; m < 4; m++){
      int rbase = m0 + wm * 64 + m * 16 + fq * 4;
      f32x4 v = acc[m][n];
      #pragma unroll
      for (int i = 0; i < 4; i++){
        int mrow = rbase + i;
        if (mrow < ne){
          int tok = lst[mrow];
          float val = v[i] + bv;
          if (PHASE2){
            pOut[((size_t)sk * T_TOK + tok) * DM + col] = val;
          } else {
            float gl = 0.5f * val * (1.0f + erff(val * 0.70710678118654752f));
            hOut[(size_t)tok * HID + col] = f2bf(gl);
          }
        }
      }
    }
  }
}

// out = gate * (part0+part1+part2+part3)   (b2 already in part0)
__global__ __launch_bounds__(256) void reduce_kernel(
    const float* __restrict__ part, const float* __restrict__ gate,
    float* __restrict__ out)
{
  size_t i = (size_t)blockIdx.x * 256 + threadIdx.x;     // float4 index
  constexpr size_t S = (size_t)T_TOK * DM / 4;
  const float4* p = (const float4*)part;
  float4 a = p[i], b = p[i + S], c = p[i + 2 * S], d = p[i + 3 * S];
  float g = gate[i >> 8];                                // 256 float4 per row
  float4 o;
  o.x = (a.x + b.x + c.x + d.x) * g;
  o.y = (a.y + b.y + c.y + d.y) * g;
  o.z = (a.z + b.z + c.z + d.z) * g;
  o.w = (a.w + b.w + c.w + d.w) * g;
  ((float4*)out)[i] = o;
}

extern "C" void kernel_launch(void* const* d_in, const int* in_sizes, int n_in,
                              void* d_out, int out_size, void* d_ws, size_t ws_size,
                              hipStream_t stream) {
  const float* x   = (const float*)d_in[0];
  const float* gw  = (const float*)d_in[1];
  const float* w1  = (const float*)d_in[2];
  const float* b1  = (const float*)d_in[3];
  const float* w2  = (const float*)d_in[4];
  const float* b2  = (const float*)d_in[5];

  char* ws = (char*)d_ws;
  float* gateo = (float*)(ws + GATE_OFF);
  int*   cnt   = (int*)  (ws + CNT_OFF);
  int*   list  = (int*)  (ws + LIST_OFF);
  float* probs = (float*)(ws + PROBS_OFF);
  u16*   xb    = (u16*)  (ws + XB_OFF);
  u16*   h     = (u16*)  (ws + H_OFF);
  float* part  = (float*)(ws + PART_OFF);

  float* out = (float*)d_out;
  float* aux = out + (size_t)T_TOK * DM;

  hipLaunchKernelGGL(zero_cnt_kernel, dim3(1), dim3(64), 0, stream, cnt);
  hipLaunchKernelGGL(gate_kernel, dim3(T_TOK / 4), dim3(256), 0, stream,
                     x, gw, gateo, cnt, list, probs, xb);
  hipLaunchKernelGGL(aux_kernel, dim3(1), dim3(256), 0, stream, probs, cnt, aux);

  // GEMM1: xb[tok,1024] x w1[e][4096][1024] -> h[tok][4096]
  //   window = 4mt x 8nt (c = nt-group of 4); grid = 2048 (worst-case windows)
  hipLaunchKernelGGL((ffn_gemm<DM, DM, HID, 16, false>),
                     dim3(2048), dim3(256), 0, stream,
                     xb, w1, b1, cnt, list, h, (float*)nullptr);
  // GEMM2: h[tok,4096] x w2[e][1024][4096] -> PART[sk][tok][1024], split-K=4
  //   window = 4mt x 8nt at fixed sk (c = sk); grid = 2048
  hipLaunchKernelGGL((ffn_gemm<HID, HID, DM, 16, true>),
                     dim3(2048), dim3(256), 0, stream,
                     h, w2, b2, cnt, list, (u16*)nullptr, part);
  hipLaunchKernelGGL(reduce_kernel, dim3(T_TOK * DM / 4 / 256), dim3(256), 0, stream,
                     part, gateo, out);
}